// Round 1
// baseline (1303.740 us; speedup 1.0000x reference)
//
#include <hip/hip_runtime.h>
#include <cstddef>

// ---------------------------------------------------------------------------
// CNN1D_LSTM1: fused pipeline for MI355X
//   K_A prep:   w_eff[i][k][o] = compose(depthwise, pointwise); repack w_c2
//   K_B conv1:  16->32 k30 eff-conv + leaky           (fp32 VALU)
//   K_C pool1:  maxpool k20 s5 ceil -> 811
//   K_D conv2:  32->64 k10 + leaky                    (fp32 VALU)
//   K_E branch: adaptive maxpool + conv(64->4,k3,p1) + leaky + Xg precompute
//   K_F lstm:   persistent per-branch block, MFMA 16x16x32 bf16 recurrent step
//   K_G head:   2->1 linear + sigmoid
// ---------------------------------------------------------------------------

typedef __attribute__((ext_vector_type(8))) short bf16x8;
typedef __attribute__((ext_vector_type(4))) float f32x4;

__device__ __forceinline__ unsigned short f2bf(float f) {
    unsigned u = __float_as_uint(f);
    u += 0x7fffu + ((u >> 16) & 1u);   // RNE
    return (unsigned short)(u >> 16);
}
__device__ __forceinline__ float bf2f(unsigned short h) {
    return __uint_as_float(((unsigned)h) << 16);
}
__device__ __forceinline__ float sigm(float x) { return 1.0f / (1.0f + __expf(-x)); }
__device__ __forceinline__ float tanh_(float x) { return 2.0f / (1.0f + __expf(-2.0f * x)) - 1.0f; }
__device__ __forceinline__ float leaky(float v) { return v >= 0.0f ? v : 0.01f * v; }

// ---------------------------------------------------------------------------
// K_A: effective conv1 weights + w_c2 repack ([o][c][k] -> [c][k][o])
__global__ void prep_kernel(const float* __restrict__ w_dw, const float* __restrict__ b_dw,
                            const float* __restrict__ w_pw, const float* __restrict__ b_pw,
                            const float* __restrict__ w_c2,
                            float* __restrict__ w_eff, float* __restrict__ b_eff,
                            float* __restrict__ wc2r) {
    const int tid = threadIdx.x;
    // w_eff[(i*30+k)*32 + o]
    for (int idx = tid; idx < 15360; idx += 256) {
        int o = idx & 31, ik = idx >> 5;
        int i = ik / 30, k = ik - i * 30;
        float s = 0.0f;
        for (int j = 0; j < 16; ++j)
            s += w_pw[o * 256 + i * 16 + j] * w_dw[(i * 16 + j) * 30 + k];
        w_eff[idx] = s;
    }
    if (tid < 32) {
        float s = b_pw[tid];
        for (int c = 0; c < 256; ++c) s += w_pw[tid * 256 + c] * b_dw[c];
        b_eff[tid] = s;
    }
    // wc2r[(c*10+k)*64 + o] = w_c2[o][c][k]
    for (int idx = tid; idx < 20480; idx += 256) {
        int o = idx & 63, ck = idx >> 6;
        int c = ck / 10, k = ck - c * 10;
        wc2r[idx] = w_c2[o * 320 + c * 10 + k];
    }
}

// ---------------------------------------------------------------------------
// K_B: conv 16->32 k30 over L=4096 -> 4067, + leaky.  grid (16,64), block 256
__global__ __launch_bounds__(256) void conv1_kernel(const float* __restrict__ X,
                                                    const float* __restrict__ w_eff,
                                                    const float* __restrict__ b_eff,
                                                    float* __restrict__ S1) {
    const int b = blockIdx.y;
    const int l0 = blockIdx.x * 256;
    const int tid = threadIdx.x;
    __shared__ float Xs[16 * 285];
    for (int i = tid; i < 16 * 285; i += 256) {
        int ch = i / 285, p = i - ch * 285;
        int gl = l0 + p;
        Xs[i] = (gl < 4096) ? X[((size_t)b * 16 + ch) * 4096 + gl] : 0.0f;
    }
    __syncthreads();
    float acc[32];
#pragma unroll
    for (int o = 0; o < 32; ++o) acc[o] = 0.0f;
    for (int i = 0; i < 16; ++i) {
        for (int k = 0; k < 30; ++k) {
            float xv = Xs[i * 285 + tid + k];
            const float* wp = w_eff + (i * 30 + k) * 32;  // wave-uniform -> s_load
#pragma unroll
            for (int o = 0; o < 32; ++o) acc[o] = fmaf(xv, wp[o], acc[o]);
        }
    }
    const int l = l0 + tid;
    if (l < 4067) {
#pragma unroll
        for (int o = 0; o < 32; ++o)
            S1[((size_t)b * 32 + o) * 4067 + l] = leaky(acc[o] + b_eff[o]);
    }
}

// ---------------------------------------------------------------------------
// K_C: maxpool k20 s5 ceil: (64,32,4067) -> (64,32,811)
__global__ void pool1_kernel(const float* __restrict__ S1, float* __restrict__ S2) {
    int idx = blockIdx.x * 256 + threadIdx.x;
    if (idx >= 64 * 32 * 811) return;
    int t = idx % 811;
    int bc = idx / 811;
    const float* row = S1 + (size_t)bc * 4067;
    int start = 5 * t;
    int end = start + 20; if (end > 4067) end = 4067;
    float m = row[start];
    for (int p = start + 1; p < end; ++p) m = fmaxf(m, row[p]);
    S2[idx] = m;
}

// ---------------------------------------------------------------------------
// K_D: conv 32->64 k10: 811 -> 802, + leaky.  grid (4,64), block 256
__global__ __launch_bounds__(256) void conv2_kernel(const float* __restrict__ S2,
                                                    const float* __restrict__ wc2r,
                                                    const float* __restrict__ b_c2,
                                                    float* __restrict__ S3) {
    const int b = blockIdx.y;
    const int l0 = blockIdx.x * 201;
    const int tid = threadIdx.x;
    __shared__ float Xs[32 * 210];
    for (int i = tid; i < 32 * 210; i += 256) {
        int ch = i / 210, p = i - ch * 210;
        int gl = l0 + p;
        Xs[i] = (gl < 811) ? S2[((size_t)b * 32 + ch) * 811 + gl] : 0.0f;
    }
    __syncthreads();
    float acc[64];
#pragma unroll
    for (int o = 0; o < 64; ++o) acc[o] = 0.0f;
    if (tid < 201) {
        for (int c = 0; c < 32; ++c) {
            for (int k = 0; k < 10; ++k) {
                float xv = Xs[c * 210 + tid + k];
                const float* wp = wc2r + (c * 10 + k) * 64;  // wave-uniform
#pragma unroll
                for (int o = 0; o < 64; ++o) acc[o] = fmaf(xv, wp[o], acc[o]);
            }
        }
        const int l = l0 + tid;
        if (l < 802) {
#pragma unroll
            for (int o = 0; o < 64; ++o)
                S3[((size_t)b * 64 + o) * 802 + l] = leaky(acc[o] + b_c2[o]);
        }
    }
}

// ---------------------------------------------------------------------------
// K_E: per (batch, branch): adaptive maxpool + conv(64->4,k3,p1)+leaky + Xg
// Xg[t][b][n] = b_ih[n]+b_hh[n] + sum_k w_ih[n][k]*xc[b][k][t]
// grid (64,2), block 256
__global__ __launch_bounds__(256) void branch_pre_kernel(
    const float* __restrict__ S3,
    const float* __restrict__ w_sc0, const float* __restrict__ b_sc0,
    const float* __restrict__ w_ih0, const float* __restrict__ b_ih0, const float* __restrict__ b_hh0,
    const float* __restrict__ w_sc1, const float* __restrict__ b_sc1,
    const float* __restrict__ w_ih1, const float* __restrict__ b_ih1, const float* __restrict__ b_hh1,
    float* __restrict__ Xg0, float* __restrict__ Xg1) {
    const int b = blockIdx.x;
    const int br = blockIdx.y;
    const int T = (br == 0) ? 300 : 100;
    const float* w_sc = (br == 0) ? w_sc0 : w_sc1;
    const float* b_sc = (br == 0) ? b_sc0 : b_sc1;
    const float* w_ih = (br == 0) ? w_ih0 : w_ih1;
    const float* b_ih = (br == 0) ? b_ih0 : b_ih1;
    const float* b_hh = (br == 0) ? b_hh0 : b_hh1;
    float* Xg = (br == 0) ? Xg0 : Xg1;

    __shared__ float xrow[802];
    __shared__ float bufP[401], bufQ[401];
    __shared__ float pbuf[302];          // zero-padded halo for conv p=1
    __shared__ float accb[4][300];

    const int tid = threadIdx.x;
    for (int i = tid; i < 4 * 300; i += 256) (&accb[0][0])[i] = 0.0f;
    for (int i = tid; i < 302; i += 256) pbuf[i] = 0.0f;
    __syncthreads();

    for (int c = 0; c < 64; ++c) {
        for (int i = tid; i < 802; i += 256)
            xrow[i] = S3[((size_t)b * 64 + c) * 802 + i];
        __syncthreads();

        if (br == 0) {
            // adaptive pool bin=300: s=2, k=204 == max over m2[t..t+101]
            for (int q = tid; q < 401; q += 256)
                bufP[q] = fmaxf(xrow[2 * q], xrow[2 * q + 1]);
            __syncthreads();
            float* src = bufP; float* dst = bufQ; int len = 401;
            for (int sp = 1; sp <= 32; sp <<= 1) {   // sparse-table doubling
                int nl = len - sp;
                for (int q = tid; q < nl; q += 256) dst[q] = fmaxf(src[q], src[q + sp]);
                __syncthreads();
                float* tmp = src; src = dst; dst = tmp; len = nl;
            }
            // window of 102 m2 elems = [t,t+64) U [t+38,t+102)
            for (int t = tid; t < 300; t += 256) pbuf[1 + t] = fmaxf(src[t], src[t + 38]);
            __syncthreads();
        } else {
            // bin=100: s=8, k=10 direct
            for (int t = tid; t < 100; t += 256) {
                float m = xrow[8 * t];
#pragma unroll
                for (int p = 1; p < 10; ++p) m = fmaxf(m, xrow[8 * t + p]);
                pbuf[1 + t] = m;
            }
            __syncthreads();
        }

        // conv k=3 p=1 accumulate (thread t owns accb[.][t])
        for (int t = tid; t < T; t += 256) {
            float pm1 = pbuf[t], p0 = pbuf[t + 1], pp1 = pbuf[t + 2];
#pragma unroll
            for (int o = 0; o < 4; ++o) {
                const float* w = w_sc + o * 192 + c * 3;
                accb[o][t] += w[0] * pm1 + w[1] * p0 + w[2] * pp1;
            }
        }
        __syncthreads();
    }

    // bias + leaky -> xc in accb
    for (int i = tid; i < 4 * T; i += 256) {
        int o = i / T, t = i - o * T;
        accb[o][t] = leaky(accb[o][t] + b_sc[o]);
    }
    __syncthreads();

    // Xg: 256 threads = 256 gate columns
    {
        const int n = tid;
        const float4 w4 = *(const float4*)(w_ih + n * 4);
        const float bias = b_ih[n] + b_hh[n];
        for (int t = 0; t < T; ++t) {
            float v = bias + w4.x * accb[0][t] + w4.y * accb[1][t]
                           + w4.z * accb[2][t] + w4.w * accb[3][t];
            Xg[((size_t)t * 64 + b) * 256 + n] = v;
        }
    }
}

// ---------------------------------------------------------------------------
// K_F: persistent LSTM. grid=2 (branch), block=1024 (16 waves).
// Wave w: mt=w&3 (batch tile), hb=w>>2 (hidden block). 4 tiles = gates i,f,g,o.
// MFMA 16x16x32 bf16: A[m=lane&15][k=quad*8+j]; B[n=lane&15][k=quad*8+j];
// C/D: col=lane&15, row=quad*4+reg   (m89/m91-verified layouts)
#define HPAD 72
__global__ __launch_bounds__(1024) void lstm_kernel(
    const float* __restrict__ Xg0, const float* __restrict__ Xg1,
    const float* __restrict__ Whh0, const float* __restrict__ Whh1,
    const float* __restrict__ wl0, const float* __restrict__ bl0,
    const float* __restrict__ wl1, const float* __restrict__ bl1,
    float* __restrict__ br_out) {
    const int br = blockIdx.x;
    const int T = (br == 0) ? 300 : 100;
    const float* Xg = (br == 0) ? Xg0 : Xg1;
    const float* Whh = (br == 0) ? Whh0 : Whh1;
    const float* wl = (br == 0) ? wl0 : wl1;
    const float* bl = (br == 0) ? bl0 : bl1;

    __shared__ __align__(16) unsigned short hb_lds[2][64][HPAD];

    const int tid = threadIdx.x;
    const int w = tid >> 6, lane = tid & 63, quad = lane >> 4, l16 = lane & 15;
    const int mt = w & 3, hbk = w >> 2;
    const int hidx = hbk * 16 + l16;   // hidden unit this lane owns
    const int arow = mt * 16 + l16;    // A-operand row (batch)

    // Preload recurrent weights as bf16 B-fragments: B[k][n] = Whh[n][k]
    bf16x8 Bf[4][2];
#pragma unroll
    for (int g = 0; g < 4; ++g) {
        const int n = g * 64 + hidx;
#pragma unroll
        for (int kc = 0; kc < 2; ++kc) {
            const float* src = Whh + n * 64 + kc * 32 + quad * 8;
            bf16x8 v;
#pragma unroll
            for (int j = 0; j < 8; ++j) v[j] = (short)f2bf(src[j]);
            Bf[g][kc] = v;
        }
    }

    // h0 = 0
    for (int i = tid; i < 64 * HPAD; i += 1024) hb_lds[0][0][i] = 0;

    int brow[4];
#pragma unroll
    for (int r = 0; r < 4; ++r) brow[r] = mt * 16 + quad * 4 + r;

    float c[4] = {0.f, 0.f, 0.f, 0.f};

    // prefetch Xg[0]
    float xg[4][4];
#pragma unroll
    for (int g = 0; g < 4; ++g)
#pragma unroll
        for (int r = 0; r < 4; ++r)
            xg[g][r] = Xg[(size_t)brow[r] * 256 + g * 64 + hidx];

    __syncthreads();

    for (int t = 0; t < T; ++t) {
        const unsigned short* hrow = &hb_lds[t & 1][arow][0];
        bf16x8 A0 = *(const bf16x8*)(hrow + quad * 8);
        bf16x8 A1 = *(const bf16x8*)(hrow + 32 + quad * 8);

        f32x4 ac[4];
#pragma unroll
        for (int g = 0; g < 4; ++g) {
            ac[g][0] = xg[g][0]; ac[g][1] = xg[g][1];
            ac[g][2] = xg[g][2]; ac[g][3] = xg[g][3];
        }

        if (t + 1 < T) {  // prefetch next step's input-part gates
#pragma unroll
            for (int g = 0; g < 4; ++g)
#pragma unroll
                for (int r = 0; r < 4; ++r)
                    xg[g][r] = Xg[((size_t)(t + 1) * 64 + brow[r]) * 256 + g * 64 + hidx];
        }

#pragma unroll
        for (int g = 0; g < 4; ++g) {
            ac[g] = __builtin_amdgcn_mfma_f32_16x16x32_bf16(A0, Bf[g][0], ac[g], 0, 0, 0);
            ac[g] = __builtin_amdgcn_mfma_f32_16x16x32_bf16(A1, Bf[g][1], ac[g], 0, 0, 0);
        }

        const int nb = (t + 1) & 1;
#pragma unroll
        for (int r = 0; r < 4; ++r) {
            float iv = sigm(ac[0][r]);
            float fv = sigm(ac[1][r]);
            float gv = tanh_(ac[2][r]);
            float ov = sigm(ac[3][r]);
            float cs = fv * c[r] + iv * gv;
            c[r] = cs;
            hb_lds[nb][brow[r]][hidx] = f2bf(ov * tanh_(cs));
        }
        __syncthreads();
    }

    // final linear: out[b] = h_T[b,:] . wl + bl
    if (tid < 64) {
        const unsigned short* hrow = &hb_lds[T & 1][tid][0];
        float s = bl[0];
        for (int j = 0; j < 64; ++j) s += bf2f(hrow[j]) * wl[j];
        br_out[br * 64 + tid] = s;
    }
}

// ---------------------------------------------------------------------------
// K_G: head: sigmoid(w0*br0 + w1*br1 + b)
__global__ void head_kernel(const float* __restrict__ brv, const float* __restrict__ w_rul,
                            const float* __restrict__ b_rul, float* __restrict__ out) {
    int b = threadIdx.x;
    float v = w_rul[0] * brv[b] + w_rul[1] * brv[64 + b] + b_rul[0];
    out[b] = 1.0f / (1.0f + __expf(-v));
}

// ---------------------------------------------------------------------------
extern "C" void kernel_launch(void* const* d_in, const int* in_sizes, int n_in,
                              void* d_out, int out_size, void* d_ws, size_t ws_size,
                              hipStream_t stream) {
    const float* X     = (const float*)d_in[0];
    const float* w_dw  = (const float*)d_in[1];
    const float* b_dw  = (const float*)d_in[2];
    const float* w_pw  = (const float*)d_in[3];
    const float* b_pw  = (const float*)d_in[4];
    const float* w_c2  = (const float*)d_in[5];
    const float* b_c2  = (const float*)d_in[6];
    const float* w_sc0 = (const float*)d_in[7];
    const float* b_sc0 = (const float*)d_in[8];
    const float* w_ih0 = (const float*)d_in[9];
    const float* b_ih0 = (const float*)d_in[10];
    const float* w_hh0 = (const float*)d_in[11];
    const float* b_hh0 = (const float*)d_in[12];
    const float* w_l0  = (const float*)d_in[13];
    const float* b_l0  = (const float*)d_in[14];
    const float* w_sc1 = (const float*)d_in[15];
    const float* b_sc1 = (const float*)d_in[16];
    const float* w_ih1 = (const float*)d_in[17];
    const float* b_ih1 = (const float*)d_in[18];
    const float* w_hh1 = (const float*)d_in[19];
    const float* b_hh1 = (const float*)d_in[20];
    const float* w_l1  = (const float*)d_in[21];
    const float* b_l1  = (const float*)d_in[22];
    const float* w_rul = (const float*)d_in[23];
    const float* b_rul = (const float*)d_in[24];

    float* ws = (float*)d_ws;
    // region0: S1 (8,329,216 f)  -> reused as Xg0 (4,915,200 f) after pool1
    // region1: S2 (1,660,928 f)  -> reused as Xg1 (1,638,400 f) after conv2
    // region2: S3 (3,284,992 f)
    // region3: small params
    float* S1    = ws;
    float* Xg0   = ws;
    float* S2    = ws + 8329216;
    float* Xg1   = S2;
    float* S3    = ws + 9990144;
    float* w_eff = ws + 13275136;
    float* b_eff = w_eff + 15360;
    float* wc2r  = b_eff + 32;
    float* brbuf = wc2r + 20480;   // 128 floats; total ~50.8 MiB

    prep_kernel<<<1, 256, 0, stream>>>(w_dw, b_dw, w_pw, b_pw, w_c2, w_eff, b_eff, wc2r);
    conv1_kernel<<<dim3(16, 64), 256, 0, stream>>>(X, w_eff, b_eff, S1);
    pool1_kernel<<<6488, 256, 0, stream>>>(S1, S2);
    conv2_kernel<<<dim3(4, 64), 256, 0, stream>>>(S2, wc2r, b_c2, S3);
    branch_pre_kernel<<<dim3(64, 2), 256, 0, stream>>>(
        S3, w_sc0, b_sc0, w_ih0, b_ih0, b_hh0,
            w_sc1, b_sc1, w_ih1, b_ih1, b_hh1, Xg0, Xg1);
    lstm_kernel<<<2, 1024, 0, stream>>>(Xg0, Xg1, w_hh0, w_hh1,
                                        w_l0, b_l0, w_l1, b_l1, brbuf);
    head_kernel<<<1, 64, 0, stream>>>(brbuf, w_rul, b_rul, (float*)d_out);
}

// Round 2
// 822.824 us; speedup vs baseline: 1.5845x; 1.5845x over previous
//
#include <hip/hip_runtime.h>
#include <cstddef>

// ---------------------------------------------------------------------------
// CNN1D_LSTM1: fused pipeline for MI355X
//   K_A prep:   w_eff[i][k][o] = compose(depthwise, pointwise); repack w_c2
//   K_B conv1:  16->32 k30 eff-conv + leaky           (fp32 VALU)
//   K_C pool1:  maxpool k20 s5 ceil -> 811
//   K_D conv2:  32->64 k10 + leaky                    (fp32 VALU)
//   K_E branch: adaptive maxpool + conv(64->4,k3,p1) + leaky + Xg precompute
//               (Xg written pre-swizzled into MFMA C-operand layout)
//   K_F lstm:   batch-split: 4 workgroups/branch x 16 batches, 4 waves each,
//               MFMA 16x16x32 bf16 recurrent step, 1 wave/SIMD
//   K_G head:   2->1 linear + sigmoid
// ---------------------------------------------------------------------------

typedef __attribute__((ext_vector_type(8))) short bf16x8;
typedef __attribute__((ext_vector_type(4))) float f32x4;

__device__ __forceinline__ unsigned short f2bf(float f) {
    unsigned u = __float_as_uint(f);
    u += 0x7fffu + ((u >> 16) & 1u);   // RNE
    return (unsigned short)(u >> 16);
}
__device__ __forceinline__ float bf2f(unsigned short h) {
    return __uint_as_float(((unsigned)h) << 16);
}
__device__ __forceinline__ float sigm(float x) { return 1.0f / (1.0f + __expf(-x)); }
__device__ __forceinline__ float tanh_(float x) { return 2.0f / (1.0f + __expf(-2.0f * x)) - 1.0f; }
__device__ __forceinline__ float leaky(float v) { return v >= 0.0f ? v : 0.01f * v; }

// ---------------------------------------------------------------------------
// K_A: effective conv1 weights + w_c2 repack ([o][c][k] -> [c][k][o])
__global__ void prep_kernel(const float* __restrict__ w_dw, const float* __restrict__ b_dw,
                            const float* __restrict__ w_pw, const float* __restrict__ b_pw,
                            const float* __restrict__ w_c2,
                            float* __restrict__ w_eff, float* __restrict__ b_eff,
                            float* __restrict__ wc2r) {
    const int tid = threadIdx.x;
    // w_eff[(i*30+k)*32 + o]
    for (int idx = tid; idx < 15360; idx += 256) {
        int o = idx & 31, ik = idx >> 5;
        int i = ik / 30, k = ik - i * 30;
        float s = 0.0f;
        for (int j = 0; j < 16; ++j)
            s += w_pw[o * 256 + i * 16 + j] * w_dw[(i * 16 + j) * 30 + k];
        w_eff[idx] = s;
    }
    if (tid < 32) {
        float s = b_pw[tid];
        for (int c = 0; c < 256; ++c) s += w_pw[tid * 256 + c] * b_dw[c];
        b_eff[tid] = s;
    }
    // wc2r[(c*10+k)*64 + o] = w_c2[o][c][k]
    for (int idx = tid; idx < 20480; idx += 256) {
        int o = idx & 63, ck = idx >> 6;
        int c = ck / 10, k = ck - c * 10;
        wc2r[idx] = w_c2[o * 320 + c * 10 + k];
    }
}

// ---------------------------------------------------------------------------
// K_B: conv 16->32 k30 over L=4096 -> 4067, + leaky.  grid (16,64), block 256
__global__ __launch_bounds__(256) void conv1_kernel(const float* __restrict__ X,
                                                    const float* __restrict__ w_eff,
                                                    const float* __restrict__ b_eff,
                                                    float* __restrict__ S1) {
    const int b = blockIdx.y;
    const int l0 = blockIdx.x * 256;
    const int tid = threadIdx.x;
    __shared__ float Xs[16 * 285];
    for (int i = tid; i < 16 * 285; i += 256) {
        int ch = i / 285, p = i - ch * 285;
        int gl = l0 + p;
        Xs[i] = (gl < 4096) ? X[((size_t)b * 16 + ch) * 4096 + gl] : 0.0f;
    }
    __syncthreads();
    float acc[32];
#pragma unroll
    for (int o = 0; o < 32; ++o) acc[o] = 0.0f;
    for (int i = 0; i < 16; ++i) {
        for (int k = 0; k < 30; ++k) {
            float xv = Xs[i * 285 + tid + k];
            const float* wp = w_eff + (i * 30 + k) * 32;  // wave-uniform -> s_load
#pragma unroll
            for (int o = 0; o < 32; ++o) acc[o] = fmaf(xv, wp[o], acc[o]);
        }
    }
    const int l = l0 + tid;
    if (l < 4067) {
#pragma unroll
        for (int o = 0; o < 32; ++o)
            S1[((size_t)b * 32 + o) * 4067 + l] = leaky(acc[o] + b_eff[o]);
    }
}

// ---------------------------------------------------------------------------
// K_C: maxpool k20 s5 ceil: (64,32,4067) -> (64,32,811)
__global__ void pool1_kernel(const float* __restrict__ S1, float* __restrict__ S2) {
    int idx = blockIdx.x * 256 + threadIdx.x;
    if (idx >= 64 * 32 * 811) return;
    int t = idx % 811;
    int bc = idx / 811;
    const float* row = S1 + (size_t)bc * 4067;
    int start = 5 * t;
    int end = start + 20; if (end > 4067) end = 4067;
    float m = row[start];
    for (int p = start + 1; p < end; ++p) m = fmaxf(m, row[p]);
    S2[idx] = m;
}

// ---------------------------------------------------------------------------
// K_D: conv 32->64 k10: 811 -> 802, + leaky.  grid (4,64), block 256
__global__ __launch_bounds__(256) void conv2_kernel(const float* __restrict__ S2,
                                                    const float* __restrict__ wc2r,
                                                    const float* __restrict__ b_c2,
                                                    float* __restrict__ S3) {
    const int b = blockIdx.y;
    const int l0 = blockIdx.x * 201;
    const int tid = threadIdx.x;
    __shared__ float Xs[32 * 210];
    for (int i = tid; i < 32 * 210; i += 256) {
        int ch = i / 210, p = i - ch * 210;
        int gl = l0 + p;
        Xs[i] = (gl < 811) ? S2[((size_t)b * 32 + ch) * 811 + gl] : 0.0f;
    }
    __syncthreads();
    float acc[64];
#pragma unroll
    for (int o = 0; o < 64; ++o) acc[o] = 0.0f;
    if (tid < 201) {
        for (int c = 0; c < 32; ++c) {
            for (int k = 0; k < 10; ++k) {
                float xv = Xs[c * 210 + tid + k];
                const float* wp = wc2r + (c * 10 + k) * 64;  // wave-uniform
#pragma unroll
                for (int o = 0; o < 64; ++o) acc[o] = fmaf(xv, wp[o], acc[o]);
            }
        }
        const int l = l0 + tid;
        if (l < 802) {
#pragma unroll
            for (int o = 0; o < 64; ++o)
                S3[((size_t)b * 64 + o) * 802 + l] = leaky(acc[o] + b_c2[o]);
        }
    }
}

// ---------------------------------------------------------------------------
// K_E: per (batch, branch): adaptive maxpool + conv(64->4,k3,p1)+leaky + Xg
// Xg value[t][b][n] = b_ih[n]+b_hh[n] + sum_k w_ih[n][k]*xc[b][k][t]
// written pre-swizzled to MFMA-C layout:
//   bt=b>>4, quad=(b>>2)&3, r=b&3, g=n>>6, hidx=n&63, w=hidx>>4, l16=hidx&15
//   idx = (((t*4+bt)*4 + w)*64 + quad*16+l16)*16 + g*4 + r
// grid (64,2), block 256
__global__ __launch_bounds__(256) void branch_pre_kernel(
    const float* __restrict__ S3,
    const float* __restrict__ w_sc0, const float* __restrict__ b_sc0,
    const float* __restrict__ w_ih0, const float* __restrict__ b_ih0, const float* __restrict__ b_hh0,
    const float* __restrict__ w_sc1, const float* __restrict__ b_sc1,
    const float* __restrict__ w_ih1, const float* __restrict__ b_ih1, const float* __restrict__ b_hh1,
    float* __restrict__ Xg0, float* __restrict__ Xg1) {
    const int b = blockIdx.x;
    const int br = blockIdx.y;
    const int T = (br == 0) ? 300 : 100;
    const float* w_sc = (br == 0) ? w_sc0 : w_sc1;
    const float* b_sc = (br == 0) ? b_sc0 : b_sc1;
    const float* w_ih = (br == 0) ? w_ih0 : w_ih1;
    const float* b_ih = (br == 0) ? b_ih0 : b_ih1;
    const float* b_hh = (br == 0) ? b_hh0 : b_hh1;
    float* Xg = (br == 0) ? Xg0 : Xg1;

    __shared__ float xrow[802];
    __shared__ float bufP[401], bufQ[401];
    __shared__ float pbuf[302];          // zero-padded halo for conv p=1
    __shared__ float accb[4][300];

    const int tid = threadIdx.x;
    for (int i = tid; i < 4 * 300; i += 256) (&accb[0][0])[i] = 0.0f;
    for (int i = tid; i < 302; i += 256) pbuf[i] = 0.0f;
    __syncthreads();

    for (int c = 0; c < 64; ++c) {
        for (int i = tid; i < 802; i += 256)
            xrow[i] = S3[((size_t)b * 64 + c) * 802 + i];
        __syncthreads();

        if (br == 0) {
            // adaptive pool bin=300: s=2, k=204 == max over m2[t..t+101]
            for (int q = tid; q < 401; q += 256)
                bufP[q] = fmaxf(xrow[2 * q], xrow[2 * q + 1]);
            __syncthreads();
            float* src = bufP; float* dst = bufQ; int len = 401;
            for (int sp = 1; sp <= 32; sp <<= 1) {   // sparse-table doubling
                int nl = len - sp;
                for (int q = tid; q < nl; q += 256) dst[q] = fmaxf(src[q], src[q + sp]);
                __syncthreads();
                float* tmp = src; src = dst; dst = tmp; len = nl;
            }
            // window of 102 m2 elems = [t,t+64) U [t+38,t+102)
            for (int t = tid; t < 300; t += 256) pbuf[1 + t] = fmaxf(src[t], src[t + 38]);
            __syncthreads();
        } else {
            // bin=100: s=8, k=10 direct
            for (int t = tid; t < 100; t += 256) {
                float m = xrow[8 * t];
#pragma unroll
                for (int p = 1; p < 10; ++p) m = fmaxf(m, xrow[8 * t + p]);
                pbuf[1 + t] = m;
            }
            __syncthreads();
        }

        // conv k=3 p=1 accumulate (thread t owns accb[.][t])
        for (int t = tid; t < T; t += 256) {
            float pm1 = pbuf[t], p0 = pbuf[t + 1], pp1 = pbuf[t + 2];
#pragma unroll
            for (int o = 0; o < 4; ++o) {
                const float* w = w_sc + o * 192 + c * 3;
                accb[o][t] += w[0] * pm1 + w[1] * p0 + w[2] * pp1;
            }
        }
        __syncthreads();
    }

    // bias + leaky -> xc in accb
    for (int i = tid; i < 4 * T; i += 256) {
        int o = i / T, t = i - o * T;
        accb[o][t] = leaky(accb[o][t] + b_sc[o]);
    }
    __syncthreads();

    // Xg: 256 threads = 256 gate columns n; swizzled write
    {
        const int n = tid;
        const float4 w4 = *(const float4*)(w_ih + n * 4);
        const float bias = b_ih[n] + b_hh[n];
        const int bt = b >> 4, quad = (b >> 2) & 3, r = b & 3;
        const int g = n >> 6, hidx = n & 63;
        const int w = hidx >> 4, l16 = hidx & 15;
        const size_t off0 = (((size_t)bt * 4 + w) * 64 + quad * 16 + l16) * 16 + g * 4 + r;
        for (int t = 0; t < T; ++t) {
            float v = bias + w4.x * accb[0][t] + w4.y * accb[1][t]
                           + w4.z * accb[2][t] + w4.w * accb[3][t];
            Xg[(size_t)t * 16384 + off0] = v;
        }
    }
}

// ---------------------------------------------------------------------------
// K_F: batch-split persistent LSTM. grid (4 bt, 2 br), block 256 (4 waves).
// Each block owns 16 batches; wave w owns hidden block hidx = w*16+l16,
// all 4 gates (8 MFMAs/step). 1 wave/SIMD -> no issue-port contention.
// MFMA 16x16x32 bf16: A[m=lane&15][k=quad*8+j]; B[n=lane&15][k=quad*8+j];
// C/D: col=lane&15, row=quad*4+reg   (m89/m91-verified layouts)
#define HPAD 80
__global__ __launch_bounds__(256) void lstm_kernel(
    const float* __restrict__ Xg0, const float* __restrict__ Xg1,
    const float* __restrict__ Whh0, const float* __restrict__ Whh1,
    const float* __restrict__ wl0, const float* __restrict__ bl0,
    const float* __restrict__ wl1, const float* __restrict__ bl1,
    float* __restrict__ br_out) {
    const int bt = blockIdx.x;
    const int br = blockIdx.y;
    const int T = (br == 0) ? 300 : 100;
    const float* Xg = (br == 0) ? Xg0 : Xg1;
    const float* Whh = (br == 0) ? Whh0 : Whh1;
    const float* wl = (br == 0) ? wl0 : wl1;
    const float* bl = (br == 0) ? bl0 : bl1;

    __shared__ __align__(16) unsigned short h_lds[2][16][HPAD];

    const int tid = threadIdx.x;
    const int w = tid >> 6, lane = tid & 63, quad = lane >> 4, l16 = lane & 15;
    const int hidx = w * 16 + l16;     // hidden unit this lane owns

    // Preload recurrent weights as bf16 B-fragments: B[k][n] = Whh[n][k]
    bf16x8 Bf[4][2];
#pragma unroll
    for (int g = 0; g < 4; ++g) {
        const int n = g * 64 + hidx;
#pragma unroll
        for (int kc = 0; kc < 2; ++kc) {
            const float* src = Whh + n * 64 + kc * 32 + quad * 8;
            bf16x8 v;
#pragma unroll
            for (int j = 0; j < 8; ++j) v[j] = (short)f2bf(src[j]);
            Bf[g][kc] = v;
        }
    }

    // h0 = 0 (buffer 0)
    for (int i = tid; i < 16 * HPAD; i += 256) (&h_lds[0][0][0])[i] = 0;

    // per-lane Xg base: 16 contiguous floats = [g*4+r]
    const float* xp = Xg + ((size_t)bt * 4 + w) * 1024 + lane * 16;

    f32x4 xb0[4], xb1[4];
#pragma unroll
    for (int g = 0; g < 4; ++g) xb0[g] = *(const f32x4*)(xp + g * 4);          // t=0
#pragma unroll
    for (int g = 0; g < 4; ++g) xb1[g] = *(const f32x4*)(xp + 16384 + g * 4);  // t=1

    float c[4] = {0.f, 0.f, 0.f, 0.f};

    __syncthreads();

    auto step = [&](int t, f32x4* xb) {
        const unsigned short* hrow = &h_lds[t & 1][l16][0];
        bf16x8 A0 = *(const bf16x8*)(hrow + quad * 8);
        bf16x8 A1 = *(const bf16x8*)(hrow + 32 + quad * 8);
        f32x4 ac[4];
#pragma unroll
        for (int g = 0; g < 4; ++g) {
            ac[g] = __builtin_amdgcn_mfma_f32_16x16x32_bf16(A0, Bf[g][0], xb[g], 0, 0, 0);
            ac[g] = __builtin_amdgcn_mfma_f32_16x16x32_bf16(A1, Bf[g][1], ac[g], 0, 0, 0);
        }
        if (t + 2 < T) {  // prefetch 2 steps ahead into the buffer just consumed
            const float* np = xp + (size_t)(t + 2) * 16384;
#pragma unroll
            for (int g = 0; g < 4; ++g) xb[g] = *(const f32x4*)(np + g * 4);
        }
        const int nb = (t + 1) & 1;
#pragma unroll
        for (int r = 0; r < 4; ++r) {
            float iv = sigm(ac[0][r]);
            float fv = sigm(ac[1][r]);
            float gv = tanh_(ac[2][r]);
            float ov = sigm(ac[3][r]);
            float cs = fv * c[r] + iv * gv;
            c[r] = cs;
            h_lds[nb][quad * 4 + r][hidx] = f2bf(ov * tanh_(cs));
        }
        __syncthreads();
    };

    for (int t = 0; t < T; t += 2) {   // T is even (300 / 100)
        step(t, xb0);
        step(t + 1, xb1);
    }

    // final linear: out[b] = h_T[b,:] . wl + bl   (T even -> buffer 0)
    if (tid < 16) {
        const unsigned short* hrow = &h_lds[0][tid][0];
        float s = bl[0];
        for (int j = 0; j < 64; ++j) s += bf2f(hrow[j]) * wl[j];
        br_out[br * 64 + bt * 16 + tid] = s;
    }
}

// ---------------------------------------------------------------------------
// K_G: head: sigmoid(w0*br0 + w1*br1 + b)
__global__ void head_kernel(const float* __restrict__ brv, const float* __restrict__ w_rul,
                            const float* __restrict__ b_rul, float* __restrict__ out) {
    int b = threadIdx.x;
    float v = w_rul[0] * brv[b] + w_rul[1] * brv[64 + b] + b_rul[0];
    out[b] = 1.0f / (1.0f + __expf(-v));
}

// ---------------------------------------------------------------------------
extern "C" void kernel_launch(void* const* d_in, const int* in_sizes, int n_in,
                              void* d_out, int out_size, void* d_ws, size_t ws_size,
                              hipStream_t stream) {
    const float* X     = (const float*)d_in[0];
    const float* w_dw  = (const float*)d_in[1];
    const float* b_dw  = (const float*)d_in[2];
    const float* w_pw  = (const float*)d_in[3];
    const float* b_pw  = (const float*)d_in[4];
    const float* w_c2  = (const float*)d_in[5];
    const float* b_c2  = (const float*)d_in[6];
    const float* w_sc0 = (const float*)d_in[7];
    const float* b_sc0 = (const float*)d_in[8];
    const float* w_ih0 = (const float*)d_in[9];
    const float* b_ih0 = (const float*)d_in[10];
    const float* w_hh0 = (const float*)d_in[11];
    const float* b_hh0 = (const float*)d_in[12];
    const float* w_l0  = (const float*)d_in[13];
    const float* b_l0  = (const float*)d_in[14];
    const float* w_sc1 = (const float*)d_in[15];
    const float* b_sc1 = (const float*)d_in[16];
    const float* w_ih1 = (const float*)d_in[17];
    const float* b_ih1 = (const float*)d_in[18];
    const float* w_hh1 = (const float*)d_in[19];
    const float* b_hh1 = (const float*)d_in[20];
    const float* w_l1  = (const float*)d_in[21];
    const float* b_l1  = (const float*)d_in[22];
    const float* w_rul = (const float*)d_in[23];
    const float* b_rul = (const float*)d_in[24];

    float* ws = (float*)d_ws;
    // region0: S1 (8,329,216 f)  -> reused as Xg0 (4,915,200 f) after pool1
    // region1: S2 (1,660,928 f)  -> reused as Xg1 (1,638,400 f) after conv2
    // region2: S3 (3,284,992 f)
    // region3: small params
    float* S1    = ws;
    float* Xg0   = ws;
    float* S2    = ws + 8329216;
    float* Xg1   = S2;
    float* S3    = ws + 9990144;
    float* w_eff = ws + 13275136;
    float* b_eff = w_eff + 15360;
    float* wc2r  = b_eff + 32;
    float* brbuf = wc2r + 20480;   // 128 floats; total ~50.8 MiB

    prep_kernel<<<1, 256, 0, stream>>>(w_dw, b_dw, w_pw, b_pw, w_c2, w_eff, b_eff, wc2r);
    conv1_kernel<<<dim3(16, 64), 256, 0, stream>>>(X, w_eff, b_eff, S1);
    pool1_kernel<<<6488, 256, 0, stream>>>(S1, S2);
    conv2_kernel<<<dim3(4, 64), 256, 0, stream>>>(S2, wc2r, b_c2, S3);
    branch_pre_kernel<<<dim3(64, 2), 256, 0, stream>>>(
        S3, w_sc0, b_sc0, w_ih0, b_ih0, b_hh0,
            w_sc1, b_sc1, w_ih1, b_ih1, b_hh1, Xg0, Xg1);
    lstm_kernel<<<dim3(4, 2), 256, 0, stream>>>(Xg0, Xg1, w_hh0, w_hh1,
                                                w_l0, b_l0, w_l1, b_l1, brbuf);
    head_kernel<<<1, 64, 0, stream>>>(brbuf, w_rul, b_rul, (float*)d_out);
}

// Round 3
// 700.438 us; speedup vs baseline: 1.8613x; 1.1747x over previous
//
#include <hip/hip_runtime.h>
#include <cstddef>

// ---------------------------------------------------------------------------
// CNN1D_LSTM1: fused pipeline for MI355X
//   K_A prep:   w_eff[i][k][o] = compose(depthwise, pointwise); repack w_c2
//   K_B conv1:  16->32 k30 eff-conv + leaky           (fp32 VALU)
//   K_C pool1:  maxpool k20 s5 ceil -> 811
//   K_D conv2:  32->64 k10 + leaky                    (fp32 VALU)
//   K_E branch: adaptive maxpool + conv(64->4,k3,p1) + leaky + Xg precompute
//               chunked 8 channels/pass to amortize barriers
//   K_F lstm:   batch-split: 4 workgroups/branch x 16 batches, 4 waves each,
//               MFMA 16x16x32 bf16 step; fast rcp/exp activations
//   K_G head:   2->1 linear + sigmoid
// ---------------------------------------------------------------------------

typedef __attribute__((ext_vector_type(8))) short bf16x8;
typedef __attribute__((ext_vector_type(4))) float f32x4;

__device__ __forceinline__ unsigned short f2bf(float f) {
    unsigned u = __float_as_uint(f);
    u += 0x7fffu + ((u >> 16) & 1u);   // RNE
    return (unsigned short)(u >> 16);
}
__device__ __forceinline__ float bf2f(unsigned short h) {
    return __uint_as_float(((unsigned)h) << 16);
}
// fast activations: v_exp_f32 + v_rcp_f32 (no IEEE divide sequence)
__device__ __forceinline__ float sigm(float x) {
    return __builtin_amdgcn_rcpf(1.0f + __expf(-x));
}
__device__ __forceinline__ float tanh_(float x) {
    return 2.0f * __builtin_amdgcn_rcpf(1.0f + __expf(-2.0f * x)) - 1.0f;
}
__device__ __forceinline__ float leaky(float v) { return v >= 0.0f ? v : 0.01f * v; }

// ---------------------------------------------------------------------------
// K_A: effective conv1 weights + w_c2 repack ([o][c][k] -> [c][k][o])
__global__ void prep_kernel(const float* __restrict__ w_dw, const float* __restrict__ b_dw,
                            const float* __restrict__ w_pw, const float* __restrict__ b_pw,
                            const float* __restrict__ w_c2,
                            float* __restrict__ w_eff, float* __restrict__ b_eff,
                            float* __restrict__ wc2r) {
    const int tid = threadIdx.x;
    // w_eff[(i*30+k)*32 + o]
    for (int idx = tid; idx < 15360; idx += 256) {
        int o = idx & 31, ik = idx >> 5;
        int i = ik / 30, k = ik - i * 30;
        float s = 0.0f;
        for (int j = 0; j < 16; ++j)
            s += w_pw[o * 256 + i * 16 + j] * w_dw[(i * 16 + j) * 30 + k];
        w_eff[idx] = s;
    }
    if (tid < 32) {
        float s = b_pw[tid];
        for (int c = 0; c < 256; ++c) s += w_pw[tid * 256 + c] * b_dw[c];
        b_eff[tid] = s;
    }
    // wc2r[(c*10+k)*64 + o] = w_c2[o][c][k]
    for (int idx = tid; idx < 20480; idx += 256) {
        int o = idx & 63, ck = idx >> 6;
        int c = ck / 10, k = ck - c * 10;
        wc2r[idx] = w_c2[o * 320 + c * 10 + k];
    }
}

// ---------------------------------------------------------------------------
// K_B: conv 16->32 k30 over L=4096 -> 4067, + leaky.  grid (16,64), block 256
__global__ __launch_bounds__(256) void conv1_kernel(const float* __restrict__ X,
                                                    const float* __restrict__ w_eff,
                                                    const float* __restrict__ b_eff,
                                                    float* __restrict__ S1) {
    const int b = blockIdx.y;
    const int l0 = blockIdx.x * 256;
    const int tid = threadIdx.x;
    __shared__ float Xs[16 * 285];
    for (int i = tid; i < 16 * 285; i += 256) {
        int ch = i / 285, p = i - ch * 285;
        int gl = l0 + p;
        Xs[i] = (gl < 4096) ? X[((size_t)b * 16 + ch) * 4096 + gl] : 0.0f;
    }
    __syncthreads();
    float acc[32];
#pragma unroll
    for (int o = 0; o < 32; ++o) acc[o] = 0.0f;
    for (int i = 0; i < 16; ++i) {
        for (int k = 0; k < 30; ++k) {
            float xv = Xs[i * 285 + tid + k];
            const float* wp = w_eff + (i * 30 + k) * 32;  // wave-uniform -> s_load
#pragma unroll
            for (int o = 0; o < 32; ++o) acc[o] = fmaf(xv, wp[o], acc[o]);
        }
    }
    const int l = l0 + tid;
    if (l < 4067) {
#pragma unroll
        for (int o = 0; o < 32; ++o)
            S1[((size_t)b * 32 + o) * 4067 + l] = leaky(acc[o] + b_eff[o]);
    }
}

// ---------------------------------------------------------------------------
// K_C: maxpool k20 s5 ceil: (64,32,4067) -> (64,32,811)
__global__ void pool1_kernel(const float* __restrict__ S1, float* __restrict__ S2) {
    int idx = blockIdx.x * 256 + threadIdx.x;
    if (idx >= 64 * 32 * 811) return;
    int t = idx % 811;
    int bc = idx / 811;
    const float* row = S1 + (size_t)bc * 4067;
    int start = 5 * t;
    int end = start + 20; if (end > 4067) end = 4067;
    float m = row[start];
    for (int p = start + 1; p < end; ++p) m = fmaxf(m, row[p]);
    S2[idx] = m;
}

// ---------------------------------------------------------------------------
// K_D: conv 32->64 k10: 811 -> 802, + leaky.  grid (4,64), block 256
__global__ __launch_bounds__(256) void conv2_kernel(const float* __restrict__ S2,
                                                    const float* __restrict__ wc2r,
                                                    const float* __restrict__ b_c2,
                                                    float* __restrict__ S3) {
    const int b = blockIdx.y;
    const int l0 = blockIdx.x * 201;
    const int tid = threadIdx.x;
    __shared__ float Xs[32 * 210];
    for (int i = tid; i < 32 * 210; i += 256) {
        int ch = i / 210, p = i - ch * 210;
        int gl = l0 + p;
        Xs[i] = (gl < 811) ? S2[((size_t)b * 32 + ch) * 811 + gl] : 0.0f;
    }
    __syncthreads();
    float acc[64];
#pragma unroll
    for (int o = 0; o < 64; ++o) acc[o] = 0.0f;
    if (tid < 201) {
        for (int c = 0; c < 32; ++c) {
            for (int k = 0; k < 10; ++k) {
                float xv = Xs[c * 210 + tid + k];
                const float* wp = wc2r + (c * 10 + k) * 64;  // wave-uniform
#pragma unroll
                for (int o = 0; o < 64; ++o) acc[o] = fmaf(xv, wp[o], acc[o]);
            }
        }
        const int l = l0 + tid;
        if (l < 802) {
#pragma unroll
            for (int o = 0; o < 64; ++o)
                S3[((size_t)b * 64 + o) * 802 + l] = leaky(acc[o] + b_c2[o]);
        }
    }
}

// ---------------------------------------------------------------------------
// K_E: per (batch, branch): adaptive maxpool + conv(64->4,k3,p1)+leaky + Xg
// Chunked: 8 channels per pass; max-doubling shared across the chunk so the
// 6 barrier rounds amortize 8x (80 barriers/block vs 640).
// Xg value[t][b][n] = b_ih[n]+b_hh[n] + sum_k w_ih[n][k]*xc[b][k][t]
// written pre-swizzled to MFMA-C layout:
//   bt=b>>4, quad=(b>>2)&3, r=b&3, g=n>>6, hidx=n&63, w=hidx>>4, l16=hidx&15
//   idx = (((t*4+bt)*4 + w)*64 + quad*16+l16)*16 + g*4 + r
// grid (64,2), block 256
__global__ __launch_bounds__(256) void branch_pre_kernel(
    const float* __restrict__ S3,
    const float* __restrict__ w_sc0, const float* __restrict__ b_sc0,
    const float* __restrict__ w_ih0, const float* __restrict__ b_ih0, const float* __restrict__ b_hh0,
    const float* __restrict__ w_sc1, const float* __restrict__ b_sc1,
    const float* __restrict__ w_ih1, const float* __restrict__ b_ih1, const float* __restrict__ b_hh1,
    float* __restrict__ Xg0, float* __restrict__ Xg1) {
    const int b = blockIdx.x;
    const int br = blockIdx.y;
    const int T = (br == 0) ? 300 : 100;
    const float* w_sc = (br == 0) ? w_sc0 : w_sc1;
    const float* b_sc = (br == 0) ? b_sc0 : b_sc1;
    const float* w_ih = (br == 0) ? w_ih0 : w_ih1;
    const float* b_ih = (br == 0) ? b_ih0 : b_ih1;
    const float* b_hh = (br == 0) ? b_hh0 : b_hh1;
    float* Xg = (br == 0) ? Xg0 : Xg1;

    __shared__ float xs[8][804];     // 8 channels of S3 row
    __shared__ float m2a[8][402];    // doubling buffer A
    __shared__ float m2b[8][402];    // doubling buffer B; overlaid as pb[8][302]
    __shared__ float accb[4][300];   // conv accumulators
    float* pb = &m2b[0][0];          // stride 302 in pb-mode

    const int tid = threadIdx.x;
    for (int i = tid; i < 1200; i += 256) (&accb[0][0])[i] = 0.0f;
    __syncthreads();

    for (int c0 = 0; c0 < 64; c0 += 8) {
        // load chunk
        for (int ci = 0; ci < 8; ++ci)
            for (int p = tid; p < 802; p += 256)
                xs[ci][p] = S3[((size_t)b * 64 + (c0 + ci)) * 802 + p];
        __syncthreads();

        if (br == 0) {
            // bin=300: s=2, k=204 -> window = 102 consecutive pair-maxes
            for (int ci = 0; ci < 8; ++ci)
                for (int q = tid; q < 401; q += 256)
                    m2a[ci][q] = fmaxf(xs[ci][2 * q], xs[ci][2 * q + 1]);
            __syncthreads();
            float* src = &m2a[0][0]; float* dst = &m2b[0][0];
            int len = 401;
            for (int sp = 1; sp <= 32; sp <<= 1) {   // 6 rounds; ends src==m2a
                int nl = len - sp;
                for (int ci = 0; ci < 8; ++ci)
                    for (int q = tid; q < nl; q += 256)
                        dst[ci * 402 + q] = fmaxf(src[ci * 402 + q], src[ci * 402 + q + sp]);
                __syncthreads();
                float* t2 = src; src = dst; dst = t2; len = nl;
            }
            // window 102 = [t,t+64) U [t+38,t+102)
            for (int ci = 0; ci < 8; ++ci)
                for (int t = tid; t < 300; t += 256)
                    pb[ci * 302 + 1 + t] = fmaxf(src[ci * 402 + t], src[ci * 402 + t + 38]);
            if (tid < 16) pb[(tid >> 1) * 302 + (tid & 1) * 301] = 0.0f;  // halos
            __syncthreads();
        } else {
            // bin=100: s=8, k=10 direct
            for (int ci = 0; ci < 8; ++ci)
                for (int t = tid; t < 100; t += 256) {
                    float m = xs[ci][8 * t];
#pragma unroll
                    for (int p = 1; p < 10; ++p) m = fmaxf(m, xs[ci][8 * t + p]);
                    pb[ci * 302 + 1 + t] = m;
                }
            if (tid < 16) pb[(tid >> 1) * 302 + (tid & 1) * 301] = 0.0f;
            __syncthreads();
        }

        // conv k=3 p=1 accumulate for this chunk
        for (int t = tid; t < T; t += 256) {
            float a0 = accb[0][t], a1 = accb[1][t], a2 = accb[2][t], a3 = accb[3][t];
            for (int ci = 0; ci < 8; ++ci) {
                float pm1 = pb[ci * 302 + t], p0 = pb[ci * 302 + t + 1], pp1 = pb[ci * 302 + t + 2];
                const int c = c0 + ci;
                const float* wv = w_sc + c * 3;  // + o*192
                a0 += wv[0] * pm1 + wv[1] * p0 + wv[2] * pp1;
                a1 += wv[192] * pm1 + wv[193] * p0 + wv[194] * pp1;
                a2 += wv[384] * pm1 + wv[385] * p0 + wv[386] * pp1;
                a3 += wv[576] * pm1 + wv[577] * p0 + wv[578] * pp1;
            }
            accb[0][t] = a0; accb[1][t] = a1; accb[2][t] = a2; accb[3][t] = a3;
        }
        __syncthreads();
    }

    // bias + leaky -> xc in accb
    for (int i = tid; i < 4 * T; i += 256) {
        int o = i / T, t = i - o * T;
        accb[o][t] = leaky(accb[o][t] + b_sc[o]);
    }
    __syncthreads();

    // Xg: 256 threads = 256 gate columns n; swizzled write
    {
        const int n = tid;
        const float4 w4 = *(const float4*)(w_ih + n * 4);
        const float bias = b_ih[n] + b_hh[n];
        const int bt = b >> 4, quad = (b >> 2) & 3, r = b & 3;
        const int g = n >> 6, hidx = n & 63;
        const int w = hidx >> 4, l16 = hidx & 15;
        const size_t off0 = (((size_t)bt * 4 + w) * 64 + quad * 16 + l16) * 16 + g * 4 + r;
        for (int t = 0; t < T; ++t) {
            float v = bias + w4.x * accb[0][t] + w4.y * accb[1][t]
                           + w4.z * accb[2][t] + w4.w * accb[3][t];
            Xg[(size_t)t * 16384 + off0] = v;
        }
    }
}

// ---------------------------------------------------------------------------
// K_F: batch-split persistent LSTM. grid (4 bt, 2 br), block 256 (4 waves).
// Each block owns 16 batches; wave w owns hidden block hidx = w*16+l16,
// all 4 gates (8 MFMAs/step). 1 wave/SIMD -> no issue-port contention.
// MFMA 16x16x32 bf16: A[m=lane&15][k=quad*8+j]; B[n=lane&15][k=quad*8+j];
// C/D: col=lane&15, row=quad*4+reg   (m89/m91-verified layouts)
// HPAD=72 shorts: row stride 36 dwords (144 mod 32 = 16) splits quad-rows
// across 2 bank sets (HPAD=80 put all 4 on one set -> 51200 conflicts).
#define HPAD 72
__global__ __launch_bounds__(256) void lstm_kernel(
    const float* __restrict__ Xg0, const float* __restrict__ Xg1,
    const float* __restrict__ Whh0, const float* __restrict__ Whh1,
    const float* __restrict__ wl0, const float* __restrict__ bl0,
    const float* __restrict__ wl1, const float* __restrict__ bl1,
    float* __restrict__ br_out) {
    const int bt = blockIdx.x;
    const int br = blockIdx.y;
    const int T = (br == 0) ? 300 : 100;
    const float* Xg = (br == 0) ? Xg0 : Xg1;
    const float* Whh = (br == 0) ? Whh0 : Whh1;
    const float* wl = (br == 0) ? wl0 : wl1;
    const float* bl = (br == 0) ? bl0 : bl1;

    __shared__ __align__(16) unsigned short h_lds[2][16][HPAD];

    const int tid = threadIdx.x;
    const int w = tid >> 6, lane = tid & 63, quad = lane >> 4, l16 = lane & 15;
    const int hidx = w * 16 + l16;     // hidden unit this lane owns

    // Preload recurrent weights as bf16 B-fragments: B[k][n] = Whh[n][k]
    bf16x8 Bf[4][2];
#pragma unroll
    for (int g = 0; g < 4; ++g) {
        const int n = g * 64 + hidx;
#pragma unroll
        for (int kc = 0; kc < 2; ++kc) {
            const float* src = Whh + n * 64 + kc * 32 + quad * 8;
            bf16x8 v;
#pragma unroll
            for (int j = 0; j < 8; ++j) v[j] = (short)f2bf(src[j]);
            Bf[g][kc] = v;
        }
    }

    // h0 = 0 (buffer 0)
    for (int i = tid; i < 16 * HPAD; i += 256) (&h_lds[0][0][0])[i] = 0;

    // per-lane Xg base: 16 contiguous floats = [g*4+r]
    const float* xp = Xg + ((size_t)bt * 4 + w) * 1024 + lane * 16;

    f32x4 xb0[4], xb1[4];
#pragma unroll
    for (int g = 0; g < 4; ++g) xb0[g] = *(const f32x4*)(xp + g * 4);          // t=0
#pragma unroll
    for (int g = 0; g < 4; ++g) xb1[g] = *(const f32x4*)(xp + 16384 + g * 4);  // t=1

    float c[4] = {0.f, 0.f, 0.f, 0.f};

    __syncthreads();

    auto step = [&](int t, f32x4* xb) {
        const unsigned short* hrow = &h_lds[t & 1][l16][0];
        bf16x8 A0 = *(const bf16x8*)(hrow + quad * 8);
        bf16x8 A1 = *(const bf16x8*)(hrow + 32 + quad * 8);
        f32x4 ac[4];
#pragma unroll
        for (int g = 0; g < 4; ++g) {
            ac[g] = __builtin_amdgcn_mfma_f32_16x16x32_bf16(A0, Bf[g][0], xb[g], 0, 0, 0);
            ac[g] = __builtin_amdgcn_mfma_f32_16x16x32_bf16(A1, Bf[g][1], ac[g], 0, 0, 0);
        }
        if (t + 2 < T) {  // prefetch 2 steps ahead into the buffer just consumed
            const float* np = xp + (size_t)(t + 2) * 16384;
#pragma unroll
            for (int g = 0; g < 4; ++g) xb[g] = *(const f32x4*)(np + g * 4);
        }
        const int nb = (t + 1) & 1;
#pragma unroll
        for (int r = 0; r < 4; ++r) {
            float iv = sigm(ac[0][r]);
            float fv = sigm(ac[1][r]);
            float gv = tanh_(ac[2][r]);
            float ov = sigm(ac[3][r]);
            float cs = fv * c[r] + iv * gv;
            c[r] = cs;
            h_lds[nb][quad * 4 + r][hidx] = f2bf(ov * tanh_(cs));
        }
        __syncthreads();
    };

    for (int t = 0; t < T; t += 2) {   // T is even (300 / 100)
        step(t, xb0);
        step(t + 1, xb1);
    }

    // final linear: out[b] = h_T[b,:] . wl + bl   (T even -> buffer 0)
    if (tid < 16) {
        const unsigned short* hrow = &h_lds[0][tid][0];
        float s = bl[0];
        for (int j = 0; j < 64; ++j) s += bf2f(hrow[j]) * wl[j];
        br_out[br * 64 + bt * 16 + tid] = s;
    }
}

// ---------------------------------------------------------------------------
// K_G: head: sigmoid(w0*br0 + w1*br1 + b)
__global__ void head_kernel(const float* __restrict__ brv, const float* __restrict__ w_rul,
                            const float* __restrict__ b_rul, float* __restrict__ out) {
    int b = threadIdx.x;
    float v = w_rul[0] * brv[b] + w_rul[1] * brv[64 + b] + b_rul[0];
    out[b] = sigm(v);
}

// ---------------------------------------------------------------------------
extern "C" void kernel_launch(void* const* d_in, const int* in_sizes, int n_in,
                              void* d_out, int out_size, void* d_ws, size_t ws_size,
                              hipStream_t stream) {
    const float* X     = (const float*)d_in[0];
    const float* w_dw  = (const float*)d_in[1];
    const float* b_dw  = (const float*)d_in[2];
    const float* w_pw  = (const float*)d_in[3];
    const float* b_pw  = (const float*)d_in[4];
    const float* w_c2  = (const float*)d_in[5];
    const float* b_c2  = (const float*)d_in[6];
    const float* w_sc0 = (const float*)d_in[7];
    const float* b_sc0 = (const float*)d_in[8];
    const float* w_ih0 = (const float*)d_in[9];
    const float* b_ih0 = (const float*)d_in[10];
    const float* w_hh0 = (const float*)d_in[11];
    const float* b_hh0 = (const float*)d_in[12];
    const float* w_l0  = (const float*)d_in[13];
    const float* b_l0  = (const float*)d_in[14];
    const float* w_sc1 = (const float*)d_in[15];
    const float* b_sc1 = (const float*)d_in[16];
    const float* w_ih1 = (const float*)d_in[17];
    const float* b_ih1 = (const float*)d_in[18];
    const float* w_hh1 = (const float*)d_in[19];
    const float* b_hh1 = (const float*)d_in[20];
    const float* w_l1  = (const float*)d_in[21];
    const float* b_l1  = (const float*)d_in[22];
    const float* w_rul = (const float*)d_in[23];
    const float* b_rul = (const float*)d_in[24];

    float* ws = (float*)d_ws;
    // region0: S1 (8,329,216 f)  -> reused as Xg0 (4,915,200 f) after pool1
    // region1: S2 (1,660,928 f)  -> reused as Xg1 (1,638,400 f) after conv2
    // region2: S3 (3,284,992 f)
    // region3: small params
    float* S1    = ws;
    float* Xg0   = ws;
    float* S2    = ws + 8329216;
    float* Xg1   = S2;
    float* S3    = ws + 9990144;
    float* w_eff = ws + 13275136;
    float* b_eff = w_eff + 15360;
    float* wc2r  = b_eff + 32;
    float* brbuf = wc2r + 20480;   // 128 floats; total ~50.8 MiB

    prep_kernel<<<1, 256, 0, stream>>>(w_dw, b_dw, w_pw, b_pw, w_c2, w_eff, b_eff, wc2r);
    conv1_kernel<<<dim3(16, 64), 256, 0, stream>>>(X, w_eff, b_eff, S1);
    pool1_kernel<<<6488, 256, 0, stream>>>(S1, S2);
    conv2_kernel<<<dim3(4, 64), 256, 0, stream>>>(S2, wc2r, b_c2, S3);
    branch_pre_kernel<<<dim3(64, 2), 256, 0, stream>>>(
        S3, w_sc0, b_sc0, w_ih0, b_ih0, b_hh0,
            w_sc1, b_sc1, w_ih1, b_ih1, b_hh1, Xg0, Xg1);
    lstm_kernel<<<dim3(4, 2), 256, 0, stream>>>(Xg0, Xg1, w_hh0, w_hh1,
                                                w_l0, b_l0, w_l1, b_l1, brbuf);
    head_kernel<<<1, 64, 0, stream>>>(brbuf, w_rul, b_rul, (float*)d_out);
}

// Round 4
// 457.833 us; speedup vs baseline: 2.8476x; 1.5299x over previous
//
#include <hip/hip_runtime.h>
#include <cstddef>

// ---------------------------------------------------------------------------
// CNN1D_LSTM1: fused pipeline for MI355X   (round 4: MFMA front-end)
//   K_A prep:   pack conv1 effective weights + conv2 weights into bf16
//               MFMA B-fragment order; b_eff
//   K_B conv1:  16->32 k30 as implicit-GEMM MFMA (M=64 pos, K=480) + leaky
//   K_C pool1:  maxpool k20 s5 ceil -> 811              (unchanged)
//   K_D conv2:  32->64 k10 as implicit-GEMM MFMA (K=320) + leaky
//   K_E1 pool_adapt: adaptive maxpool, one wave per (b,c) row -> bf16 P
//   K_E2 xg:    conv(64->4,k3,p1)+leaky + Xg precompute (swizzled MFMA-C)
//   K_F lstm:   batch-split MFMA 16x16x32 bf16 step      (unchanged)
//   K_G head:   2->1 linear + sigmoid                    (unchanged)
// ---------------------------------------------------------------------------

typedef __attribute__((ext_vector_type(8))) short bf16x8;
typedef __attribute__((ext_vector_type(4))) float f32x4;
typedef unsigned int uint32;

__device__ __forceinline__ unsigned short f2bf(float f) {
    unsigned u = __float_as_uint(f);
    u += 0x7fffu + ((u >> 16) & 1u);   // RNE
    return (unsigned short)(u >> 16);
}
__device__ __forceinline__ float bf2f(unsigned short h) {
    return __uint_as_float(((unsigned)h) << 16);
}
__device__ __forceinline__ float sigm(float x) {
    return __builtin_amdgcn_rcpf(1.0f + __expf(-x));
}
__device__ __forceinline__ float tanh_(float x) {
    return 2.0f * __builtin_amdgcn_rcpf(1.0f + __expf(-2.0f * x)) - 1.0f;
}
__device__ __forceinline__ float leaky(float v) { return v >= 0.0f ? v : 0.01f * v; }

// ---------------------------------------------------------------------------
// K_A: weight packs.  grid 26 blocks x 256.
// Wp1[(kc*32+n)*32 + k'] = w_eff(ch=k'&15, kappa=2kc+(k'>>4), o=n)   (15 kc)
// Wc2p[(kc*64+n)*32 + k'] = w_c2[n][ch=k'][kappa=kc]                 (10 kc)
__global__ void prep_kernel(const float* __restrict__ w_dw, const float* __restrict__ b_dw,
                            const float* __restrict__ w_pw, const float* __restrict__ b_pw,
                            const float* __restrict__ w_c2,
                            unsigned short* __restrict__ Wp1,
                            unsigned short* __restrict__ Wc2p,
                            float* __restrict__ b_eff) {
    const int bid = blockIdx.x, tid = threadIdx.x;
    if (bid < 15) {
        const int kc = bid;
        for (int it = 0; it < 4; ++it) {
            int idx = tid + it * 256;                 // 0..1023 = n(32) x k'(32)
            int n = idx >> 5, kp = idx & 31;
            int ch = kp & 15, kappa = kc * 2 + (kp >> 4);
            float s = 0.f;
            for (int j = 0; j < 16; ++j)
                s += w_pw[n * 256 + ch * 16 + j] * w_dw[(ch * 16 + j) * 30 + kappa];
            Wp1[(kc * 32 + n) * 32 + kp] = f2bf(s);
        }
    } else if (bid < 25) {
        const int kc = bid - 15;
        for (int it = 0; it < 8; ++it) {
            int idx = tid + it * 256;                 // 0..2047 = n(64) x k'(32)
            int n = idx >> 5, kp = idx & 31;
            Wc2p[(kc * 64 + n) * 32 + kp] = f2bf(w_c2[n * 320 + kp * 10 + kc]);
        }
    } else {
        if (tid < 32) {
            float s = b_pw[tid];
            for (int c = 0; c < 256; ++c) s += w_pw[tid * 256 + c] * b_dw[c];
            b_eff[tid] = s;
        }
    }
}

// ---------------------------------------------------------------------------
// K_B: conv1 implicit-GEMM.  grid (64 ltiles, 64 b), 256 thr (4 waves).
// Block: M=64 positions x N=32 outputs, K=480 = 15 chunks of 32 (kappa-pair x 16ch).
// A[m][k'] = X[b][ch=k'&15][l0+m+2kc+(k'>>4)]  via transposed LDS tile Xt[p][ch].
// Layouts per verified mapping: A[m=lane&15][k=quad*8+j], B[n=lane&15][k=quad*8+j],
// C/D col=lane&15, row=quad*4+reg.
__global__ __launch_bounds__(256) void conv1_kernel(const float* __restrict__ X,
        const unsigned short* __restrict__ Wp1, const float* __restrict__ b_eff,
        float* __restrict__ S1) {
    const int b = blockIdx.y;
    const int l0 = blockIdx.x * 64;
    const int tid = threadIdx.x;
    __shared__ __align__(16) unsigned short Xt[96 * 24];      // rows padded to 24 sh
    __shared__ __align__(16) unsigned short Wl[15 * 32 * 40]; // rows padded to 40 sh
    {   // stage weights (dword-wise, 16 dwords/row -> padded 20)
        const uint32* src = (const uint32*)Wp1;
        uint32* dst = (uint32*)Wl;
        for (int i = tid; i < 7680; i += 256) {
            int row = i >> 4, kd = i & 15;
            dst[row * 20 + kd] = src[i];
        }
    }
    for (int i = tid; i < 1536; i += 256) {                   // stage X transposed bf16
        int ch = i / 96, p = i - ch * 96;
        int l = l0 + p;
        float v = (p < 93 && l < 4096) ? X[((size_t)b * 16 + ch) * 4096 + l] : 0.f;
        Xt[p * 24 + ch] = f2bf(v);
    }
    __syncthreads();
    const int w = tid >> 6, lane = tid & 63, quad = lane >> 4, l16 = lane & 15;
    const int ki = quad >> 1, ch0 = (quad & 1) * 8;
    const int mA = w * 16 + l16;
    f32x4 acc0 = {0.f, 0.f, 0.f, 0.f}, acc1 = {0.f, 0.f, 0.f, 0.f};
#pragma unroll
    for (int kc = 0; kc < 15; ++kc) {
        bf16x8 A  = *(const bf16x8*)(Xt + (mA + 2 * kc + ki) * 24 + ch0);
        bf16x8 B0 = *(const bf16x8*)(Wl + (kc * 32 + l16) * 40 + quad * 8);
        bf16x8 B1 = *(const bf16x8*)(Wl + (kc * 32 + 16 + l16) * 40 + quad * 8);
        acc0 = __builtin_amdgcn_mfma_f32_16x16x32_bf16(A, B0, acc0, 0, 0, 0);
        acc1 = __builtin_amdgcn_mfma_f32_16x16x32_bf16(A, B1, acc1, 0, 0, 0);
    }
    const float be0 = b_eff[l16], be1 = b_eff[16 + l16];
    const int lbase = l0 + w * 16 + quad * 4;
#pragma unroll
    for (int r = 0; r < 4; ++r) {
        int l = lbase + r;
        if (l < 4067) {
            S1[((size_t)b * 32 + l16) * 4067 + l]      = leaky(acc0[r] + be0);
            S1[((size_t)b * 32 + 16 + l16) * 4067 + l] = leaky(acc1[r] + be1);
        }
    }
}

// ---------------------------------------------------------------------------
// K_C: maxpool k20 s5 ceil: (64,32,4067) -> (64,32,811)   (unchanged)
__global__ void pool1_kernel(const float* __restrict__ S1, float* __restrict__ S2) {
    int idx = blockIdx.x * 256 + threadIdx.x;
    if (idx >= 64 * 32 * 811) return;
    int t = idx % 811;
    int bc = idx / 811;
    const float* row = S1 + (size_t)bc * 4067;
    int start = 5 * t;
    int end = start + 20; if (end > 4067) end = 4067;
    float m = row[start];
    for (int p = start + 1; p < end; ++p) m = fmaxf(m, row[p]);
    S2[idx] = m;
}

// ---------------------------------------------------------------------------
// K_D: conv2 implicit-GEMM.  grid (13 ltiles, 64 b), 256 thr.
// M=64, N=64, K=320 = 10 kappa-chunks x 32 ch.  A[m][k'=ch] = S2[b][ch][l0+m+kc].
__global__ __launch_bounds__(256) void conv2_kernel(const float* __restrict__ S2,
        const unsigned short* __restrict__ Wc2p, const float* __restrict__ b_c2,
        float* __restrict__ S3) {
    const int b = blockIdx.y, l0 = blockIdx.x * 64, tid = threadIdx.x;
    __shared__ __align__(16) unsigned short At[80 * 40];
    __shared__ __align__(16) unsigned short Wl[10 * 64 * 40];
    {
        const uint32* src = (const uint32*)Wc2p;
        uint32* dst = (uint32*)Wl;
        for (int i = tid; i < 12800; i += 256) {
            int row = i >> 4, kd = i & 15;
            dst[row * 20 + kd] = src[i];
        }
    }
    for (int i = tid; i < 2560; i += 256) {
        int ch = i / 80, p = i - ch * 80;
        int l = l0 + p;
        float v = (p < 73 && l < 811) ? S2[((size_t)b * 32 + ch) * 811 + l] : 0.f;
        At[p * 40 + ch] = f2bf(v);
    }
    __syncthreads();
    const int w = tid >> 6, lane = tid & 63, quad = lane >> 4, l16 = lane & 15;
    const int mA = w * 16 + l16, ch0 = quad * 8;
    f32x4 acc[4];
#pragma unroll
    for (int nt = 0; nt < 4; ++nt) acc[nt] = (f32x4){0.f, 0.f, 0.f, 0.f};
#pragma unroll
    for (int kc = 0; kc < 10; ++kc) {
        bf16x8 A = *(const bf16x8*)(At + (mA + kc) * 40 + ch0);
#pragma unroll
        for (int nt = 0; nt < 4; ++nt) {
            bf16x8 Bf = *(const bf16x8*)(Wl + (kc * 64 + nt * 16 + l16) * 40 + quad * 8);
            acc[nt] = __builtin_amdgcn_mfma_f32_16x16x32_bf16(A, Bf, acc[nt], 0, 0, 0);
        }
    }
    const int lbase = l0 + w * 16 + quad * 4;
#pragma unroll
    for (int nt = 0; nt < 4; ++nt) {
        int o = nt * 16 + l16;
        float bc = b_c2[o];
#pragma unroll
        for (int r = 0; r < 4; ++r) {
            int l = lbase + r;
            if (l < 802) S3[((size_t)b * 64 + o) * 802 + l] = leaky(acc[nt][r] + bc);
        }
    }
}

// ---------------------------------------------------------------------------
// K_E1: adaptive maxpool, one wave per (b,c) row.  grid 2048 x 256.
// blocks <1024: branch0 (bin=300, s=2 k=204 via pairmax + 6-round doubling);
// blocks >=1024: branch1 (bin=100, s=8 k=10 direct).  Output bf16 with halo pad.
__global__ __launch_bounds__(256) void pool_adapt_kernel(const float* __restrict__ S3,
        unsigned short* __restrict__ P0, unsigned short* __restrict__ P1) {
    __shared__ float buf[4][2][402];
    const int tid = threadIdx.x, w = tid >> 6, lane = tid & 63;
    if (blockIdx.x < 1024) {
        const int gw = blockIdx.x * 4 + w;
        const int b = gw >> 6, c = gw & 63;
        const float* row = S3 + ((size_t)b * 64 + c) * 802;
        float* A = buf[w][0];
        float* B = buf[w][1];
        for (int it = 0; it < 7; ++it) {
            int q = lane + it * 64;
            if (q < 401) A[q] = fmaxf(row[2 * q], row[2 * q + 1]);
        }
        __syncthreads();
        int len = 401;
#pragma unroll
        for (int sp = 1; sp <= 32; sp <<= 1) {     // W64[q] = max m2[q..q+63]
            int nl = len - sp;
            for (int it = 0; it < 7; ++it) {
                int q = lane + it * 64;
                if (q < nl) B[q] = fmaxf(A[q], A[q + sp]);
            }
            __syncthreads();
            float* t = A; A = B; B = t; len = nl;
        }
        unsigned short* dst = P0 + ((size_t)b * 64 + c) * 302;
        for (int it = 0; it < 5; ++it) {
            int t = lane + it * 64;                // window 102 = [t,t+64)U[t+38,t+102)
            if (t < 300) dst[1 + t] = f2bf(fmaxf(A[t], A[t + 38]));
        }
        if (lane < 2) dst[lane * 301] = 0;         // conv halos
    } else {
        const int gw = (blockIdx.x - 1024) * 4 + w;
        const int b = gw >> 6, c = gw & 63;
        const float* row = S3 + ((size_t)b * 64 + c) * 802;
        unsigned short* dst = P1 + ((size_t)b * 64 + c) * 102;
        for (int it = 0; it < 2; ++it) {
            int t = lane + it * 64;
            if (t < 100) {
                float m = row[8 * t];
#pragma unroll
                for (int p = 1; p < 10; ++p) m = fmaxf(m, row[8 * t + p]);
                dst[1 + t] = f2bf(m);
            }
        }
        if (lane < 2) dst[lane * 101] = 0;
    }
}

// ---------------------------------------------------------------------------
// K_E2: conv(64->4,k3,p1)+leaky + Xg precompute, per (b,br).  grid (64,2) x 256.
// Xg written pre-swizzled to MFMA-C layout (same formula as lstm consumes).
__global__ __launch_bounds__(256) void xg_kernel(
        const unsigned short* __restrict__ P0, const unsigned short* __restrict__ P1,
        const float* __restrict__ w_sc0, const float* __restrict__ b_sc0,
        const float* __restrict__ w_ih0, const float* __restrict__ b_ih0, const float* __restrict__ b_hh0,
        const float* __restrict__ w_sc1, const float* __restrict__ b_sc1,
        const float* __restrict__ w_ih1, const float* __restrict__ b_ih1, const float* __restrict__ b_hh1,
        float* __restrict__ Xg0, float* __restrict__ Xg1) {
    const int b = blockIdx.x, br = blockIdx.y;
    const int T = br ? 100 : 300;
    const int PS = br ? 102 : 302;
    const unsigned short* Psrc = br ? P1 : P0;
    const float* w_sc = br ? w_sc1 : w_sc0;
    const float* b_sc = br ? b_sc1 : b_sc0;
    const float* w_ih = br ? w_ih1 : w_ih0;
    const float* b_ih = br ? b_ih1 : b_ih0;
    const float* b_hh = br ? b_hh1 : b_hh0;
    float* Xg = br ? Xg1 : Xg0;

    __shared__ unsigned short Ps[64 * 302];
    __shared__ float xc[4][304];
    const int tid = threadIdx.x;
    {
        const uint32* src = (const uint32*)(Psrc + (size_t)b * 64 * PS);
        uint32* dst = (uint32*)Ps;
        const int nd = 64 * PS / 2;
        for (int i = tid; i < nd; i += 256) dst[i] = src[i];
    }
    __syncthreads();
    for (int i = tid; i < 4 * T; i += 256) {
        int o = i / T, t = i - o * T;
        float sum = b_sc[o];
        const float* wv = w_sc + o * 192;
        for (int c = 0; c < 64; ++c) {
            int base = c * PS + t;
            float p0 = bf2f(Ps[base]), p1 = bf2f(Ps[base + 1]), p2 = bf2f(Ps[base + 2]);
            sum += wv[c * 3] * p0 + wv[c * 3 + 1] * p1 + wv[c * 3 + 2] * p2;
        }
        xc[o][t] = leaky(sum);
    }
    __syncthreads();
    {
        const int n = tid;
        const float4 w4 = *(const float4*)(w_ih + n * 4);
        const float bias = b_ih[n] + b_hh[n];
        const int bt = b >> 4, quad = (b >> 2) & 3, r = b & 3;
        const int g = n >> 6, hidx = n & 63;
        const int wv2 = hidx >> 4, l16 = hidx & 15;
        const size_t off0 = (((size_t)bt * 4 + wv2) * 64 + quad * 16 + l16) * 16 + g * 4 + r;
        for (int t = 0; t < T; ++t) {
            float v = bias + w4.x * xc[0][t] + w4.y * xc[1][t]
                           + w4.z * xc[2][t] + w4.w * xc[3][t];
            Xg[(size_t)t * 16384 + off0] = v;
        }
    }
}

// ---------------------------------------------------------------------------
// K_F: batch-split persistent LSTM (unchanged from round 3).
#define HPAD 72
__global__ __launch_bounds__(256) void lstm_kernel(
    const float* __restrict__ Xg0, const float* __restrict__ Xg1,
    const float* __restrict__ Whh0, const float* __restrict__ Whh1,
    const float* __restrict__ wl0, const float* __restrict__ bl0,
    const float* __restrict__ wl1, const float* __restrict__ bl1,
    float* __restrict__ br_out) {
    const int bt = blockIdx.x;
    const int br = blockIdx.y;
    const int T = (br == 0) ? 300 : 100;
    const float* Xg = (br == 0) ? Xg0 : Xg1;
    const float* Whh = (br == 0) ? Whh0 : Whh1;
    const float* wl = (br == 0) ? wl0 : wl1;
    const float* bl = (br == 0) ? bl0 : bl1;

    __shared__ __align__(16) unsigned short h_lds[2][16][HPAD];

    const int tid = threadIdx.x;
    const int w = tid >> 6, lane = tid & 63, quad = lane >> 4, l16 = lane & 15;
    const int hidx = w * 16 + l16;

    bf16x8 Bf[4][2];
#pragma unroll
    for (int g = 0; g < 4; ++g) {
        const int n = g * 64 + hidx;
#pragma unroll
        for (int kc = 0; kc < 2; ++kc) {
            const float* src = Whh + n * 64 + kc * 32 + quad * 8;
            bf16x8 v;
#pragma unroll
            for (int j = 0; j < 8; ++j) v[j] = (short)f2bf(src[j]);
            Bf[g][kc] = v;
        }
    }

    for (int i = tid; i < 16 * HPAD; i += 256) (&h_lds[0][0][0])[i] = 0;

    const float* xp = Xg + ((size_t)bt * 4 + w) * 1024 + lane * 16;

    f32x4 xb0[4], xb1[4];
#pragma unroll
    for (int g = 0; g < 4; ++g) xb0[g] = *(const f32x4*)(xp + g * 4);
#pragma unroll
    for (int g = 0; g < 4; ++g) xb1[g] = *(const f32x4*)(xp + 16384 + g * 4);

    float c[4] = {0.f, 0.f, 0.f, 0.f};

    __syncthreads();

    auto step = [&](int t, f32x4* xb) {
        const unsigned short* hrow = &h_lds[t & 1][l16][0];
        bf16x8 A0 = *(const bf16x8*)(hrow + quad * 8);
        bf16x8 A1 = *(const bf16x8*)(hrow + 32 + quad * 8);
        f32x4 ac[4];
#pragma unroll
        for (int g = 0; g < 4; ++g) {
            ac[g] = __builtin_amdgcn_mfma_f32_16x16x32_bf16(A0, Bf[g][0], xb[g], 0, 0, 0);
            ac[g] = __builtin_amdgcn_mfma_f32_16x16x32_bf16(A1, Bf[g][1], ac[g], 0, 0, 0);
        }
        if (t + 2 < T) {
            const float* np = xp + (size_t)(t + 2) * 16384;
#pragma unroll
            for (int g = 0; g < 4; ++g) xb[g] = *(const f32x4*)(np + g * 4);
        }
        const int nb = (t + 1) & 1;
#pragma unroll
        for (int r = 0; r < 4; ++r) {
            float iv = sigm(ac[0][r]);
            float fv = sigm(ac[1][r]);
            float gv = tanh_(ac[2][r]);
            float ov = sigm(ac[3][r]);
            float cs = fv * c[r] + iv * gv;
            c[r] = cs;
            h_lds[nb][quad * 4 + r][hidx] = f2bf(ov * tanh_(cs));
        }
        __syncthreads();
    };

    for (int t = 0; t < T; t += 2) {
        step(t, xb0);
        step(t + 1, xb1);
    }

    if (tid < 16) {
        const unsigned short* hrow = &h_lds[0][tid][0];
        float s = bl[0];
        for (int j = 0; j < 64; ++j) s += bf2f(hrow[j]) * wl[j];
        br_out[br * 64 + bt * 16 + tid] = s;
    }
}

// ---------------------------------------------------------------------------
__global__ void head_kernel(const float* __restrict__ brv, const float* __restrict__ w_rul,
                            const float* __restrict__ b_rul, float* __restrict__ out) {
    int b = threadIdx.x;
    float v = w_rul[0] * brv[b] + w_rul[1] * brv[64 + b] + b_rul[0];
    out[b] = sigm(v);
}

// ---------------------------------------------------------------------------
extern "C" void kernel_launch(void* const* d_in, const int* in_sizes, int n_in,
                              void* d_out, int out_size, void* d_ws, size_t ws_size,
                              hipStream_t stream) {
    const float* X     = (const float*)d_in[0];
    const float* w_dw  = (const float*)d_in[1];
    const float* b_dw  = (const float*)d_in[2];
    const float* w_pw  = (const float*)d_in[3];
    const float* b_pw  = (const float*)d_in[4];
    const float* w_c2  = (const float*)d_in[5];
    const float* b_c2  = (const float*)d_in[6];
    const float* w_sc0 = (const float*)d_in[7];
    const float* b_sc0 = (const float*)d_in[8];
    const float* w_ih0 = (const float*)d_in[9];
    const float* b_ih0 = (const float*)d_in[10];
    const float* w_hh0 = (const float*)d_in[11];
    const float* b_hh0 = (const float*)d_in[12];
    const float* w_l0  = (const float*)d_in[13];
    const float* b_l0  = (const float*)d_in[14];
    const float* w_sc1 = (const float*)d_in[15];
    const float* b_sc1 = (const float*)d_in[16];
    const float* w_ih1 = (const float*)d_in[17];
    const float* b_ih1 = (const float*)d_in[18];
    const float* w_hh1 = (const float*)d_in[19];
    const float* b_hh1 = (const float*)d_in[20];
    const float* w_l1  = (const float*)d_in[21];
    const float* b_l1  = (const float*)d_in[22];
    const float* w_rul = (const float*)d_in[23];
    const float* b_rul = (const float*)d_in[24];

    float* ws = (float*)d_ws;
    // region0 (8,329,216 f): S1 -> later Xg0 (4,915,200) + P0/P1 in its tail
    // region1 (1,660,928 f): S2 -> later Xg1
    // region2 (3,284,992 f): S3
    // region3: weight packs + small
    float* S1  = ws;
    float* Xg0 = ws;
    unsigned short* P0 = (unsigned short*)(ws + 4915200);            // 1,236,992 sh
    unsigned short* P1 = (unsigned short*)(ws + 4915200 + 618496);   //   417,792 sh
    float* S2  = ws + 8329216;
    float* Xg1 = S2;
    float* S3  = ws + 9990144;
    unsigned short* Wp1  = (unsigned short*)(ws + 13275136);         // 15,360 sh
    unsigned short* Wc2p = (unsigned short*)(ws + 13282816);         // 20,480 sh
    float* b_eff = ws + 13293056;
    float* brbuf = ws + 13293088;

    prep_kernel<<<26, 256, 0, stream>>>(w_dw, b_dw, w_pw, b_pw, w_c2, Wp1, Wc2p, b_eff);
    conv1_kernel<<<dim3(64, 64), 256, 0, stream>>>(X, Wp1, b_eff, S1);
    pool1_kernel<<<6488, 256, 0, stream>>>(S1, S2);
    conv2_kernel<<<dim3(13, 64), 256, 0, stream>>>(S2, Wc2p, b_c2, S3);
    pool_adapt_kernel<<<2048, 256, 0, stream>>>(S3, P0, P1);
    xg_kernel<<<dim3(64, 2), 256, 0, stream>>>(
        P0, P1, w_sc0, b_sc0, w_ih0, b_ih0, b_hh0,
                w_sc1, b_sc1, w_ih1, b_ih1, b_hh1, Xg0, Xg1);
    lstm_kernel<<<dim3(4, 2), 256, 0, stream>>>(Xg0, Xg1, w_hh0, w_hh1,
                                                w_l0, b_l0, w_l1, b_l1, brbuf);
    head_kernel<<<1, 64, 0, stream>>>(brbuf, w_rul, b_rul, (float*)d_out);
}